// Round 2
// baseline (2175.336 us; speedup 1.0000x reference)
//
#include <hip/hip_runtime.h>

// GptOssExperts: E=8, B=2, S=1024, H=2880, D=2880 ; T = B*S = 2048
//
// DTYPE-ADAPTIVE: a probe kernel detects whether inputs are fp32 or bf16
// (scans hidden_states u16-view for bf16-NaN exponent patterns, which occur
// w.p. ~1/256 per odd u16 iff the buffer is fp32) and writes a flag into ws.
// All loaders branch (wave-uniformly) on the flag and canonicalize:
//   x, w1, w2  -> bf16 (MFMA operands)
//   rw, b1, db -> fp32 (epilogue scalars)
// Output store branches fp32/bf16 on the same flag.
//
// Pipeline (one stream, serialized):
//   detect -> cast_small -> cast_x -> transpose(w1)->wbig -> gemm1(hid)
//          -> transpose(w2)->wbig (reuses w1t space) -> gemm2(out)
//
// ws: [flag 256B][rw_f 64K][b1_f 180K][db_f 90K][xc 11.8M][hid 94.4M][wbig 265.4M]
//     = 354.7 MiB peak.

typedef unsigned short u16;
typedef __bf16 bf16x8 __attribute__((ext_vector_type(8)));
typedef float  f32x4  __attribute__((ext_vector_type(4)));

#define T_TOK 2048
#define HDIM  2880
#define DDIM  2880
#define N1    5760   // 2*D
#define NEXP  8

__device__ __forceinline__ float bf2f(u16 h) {
    return __uint_as_float(((unsigned int)h) << 16);
}
__device__ __forceinline__ u16 f2bf(float f) {
    unsigned int u = __float_as_uint(f);
    u += 0x7fff + ((u >> 16) & 1);   // RNE
    return (u16)(u >> 16);
}
__device__ __forceinline__ float loadf(const void* p, size_t i, int isf32) {
    return isf32 ? ((const float*)p)[i] : bf2f(((const u16*)p)[i]);
}

// async global->LDS, 16B per lane; LDS side is wave-uniform base + lane*16
// (our lds pointers are lane-linear with stride 16B, consistent).
#define GLD16(gp, lp) __builtin_amdgcn_global_load_lds( \
    (const __attribute__((address_space(1))) void*)(gp), \
    (__attribute__((address_space(3))) void*)(lp), 16, 0, 0)

// ---------------------------------------------------------------------------
// Dtype probe: fp32 N(0,1) data viewed as u16 has ~1/256 of odd u16s with
// bf16-NaN/Inf exponent (0x7F80); true bf16 N(0,1) data has none.
// ---------------------------------------------------------------------------
__global__ __launch_bounds__(256) void detect_k(const u16* __restrict__ x,
                                                int* __restrict__ flag)
{
    __shared__ int cnt;
    if (threadIdx.x == 0) cnt = 0;
    __syncthreads();
    int local = 0;
    for (int i = threadIdx.x; i < 32768; i += 256)
        if ((x[i] & 0x7F80) == 0x7F80) local++;
    if (local) atomicAdd(&cnt, local);
    __syncthreads();
    if (threadIdx.x == 0) *flag = (cnt > 0) ? 1 : 0;
}

// ---------------------------------------------------------------------------
// Canonicalize small tensors to fp32: rw (T,E), b1 (E,N1), db (E,H)
// grid: 334 blocks x 256 (exactly 85504 elements)
// ---------------------------------------------------------------------------
#define NRW (T_TOK * NEXP)
#define NB1 (NEXP * N1)
#define NDB (NEXP * HDIM)
__global__ __launch_bounds__(256) void cast_small_k(
    const void* __restrict__ rw, const void* __restrict__ b1,
    const void* __restrict__ db, float* __restrict__ rw_f,
    float* __restrict__ b1_f, float* __restrict__ db_f,
    const int* __restrict__ flag)
{
    int i = blockIdx.x * 256 + threadIdx.x;
    const int isf32 = *flag;
    if (i < NRW)                  rw_f[i] = loadf(rw, i, isf32);
    else if (i < NRW + NB1)       b1_f[i - NRW] = loadf(b1, i - NRW, isf32);
    else if (i < NRW + NB1 + NDB) db_f[i - NRW - NB1] = loadf(db, i - NRW - NB1, isf32);
}

// ---------------------------------------------------------------------------
// Canonicalize x to bf16. grid: 5760 x 256, 4 elems/thread.
// ---------------------------------------------------------------------------
__global__ __launch_bounds__(256) void cast_x_k(const void* __restrict__ x,
                                                u16* __restrict__ xc,
                                                const int* __restrict__ flag)
{
    size_t i = (size_t)blockIdx.x * 256 + threadIdx.x;   // 4-elem chunk index
    if (*flag) {
        float4 v = ((const float4*)x)[i];
        ushort4 o;
        o.x = f2bf(v.x); o.y = f2bf(v.y); o.z = f2bf(v.z); o.w = f2bf(v.w);
        ((ushort4*)xc)[i] = o;
    } else {
        ((ushort4*)xc)[i] = ((const ushort4*)x)[i];
    }
}

// ---------------------------------------------------------------------------
// Transpose+cast (E, Ri, Ci) -> bf16 (E, Ci, Ri). 64x64 tiles through LDS.
// grid: (Ci/64, Ri/64, E), block 256.
// ---------------------------------------------------------------------------
__global__ __launch_bounds__(256) void transpose_cast_k(
    const void* __restrict__ in, u16* __restrict__ out, int Ri, int Ci,
    const int* __restrict__ flag)
{
    __shared__ u16 tile[64][68];
    const int tid = threadIdx.x;
    const int e  = blockIdx.z;
    const int c0 = blockIdx.x * 64;
    const int r0 = blockIdx.y * 64;
    const size_t ibase = (size_t)e * Ri * Ci + (size_t)r0 * Ci + c0;
    u16* op = out + (size_t)e * Ri * Ci + (size_t)c0 * Ri + r0;

    if (*flag) {
        const float* ip = (const float*)in + ibase;
#pragma unroll
        for (int i = 0; i < 4; ++i) {
            int ch = i * 256 + tid;
            int r = ch >> 4, c4 = ch & 15;
            float4 v = *(const float4*)(ip + (size_t)r * Ci + c4 * 4);
            u16* tp = &tile[r][c4 * 4];
            tp[0] = f2bf(v.x); tp[1] = f2bf(v.y); tp[2] = f2bf(v.z); tp[3] = f2bf(v.w);
        }
    } else {
        const u16* ip = (const u16*)in + ibase;
#pragma unroll
        for (int i = 0; i < 4; ++i) {
            int ch = i * 256 + tid;
            int r = ch >> 4, c4 = ch & 15;
            ushort4 v = *(const ushort4*)(ip + (size_t)r * Ci + c4 * 4);
            *(ushort4*)&tile[r][c4 * 4] = v;
        }
    }
    __syncthreads();
#pragma unroll
    for (int i = 0; i < 4; ++i) {
        int ch = i * 256 + tid;
        int c = ch >> 4, r4 = ch & 15;
        ushort4 v;
        v.x = tile[r4 * 4 + 0][c];
        v.y = tile[r4 * 4 + 1][c];
        v.z = tile[r4 * 4 + 2][c];
        v.w = tile[r4 * 4 + 3][c];
        *(ushort4*)(op + (size_t)c * Ri + r4 * 4) = v;
    }
}

// ---------------------------------------------------------------------------
// GEMM1 + fused bias/act/routing-scale.
//   A = xc (T,H) bf16   B = w1t (E,N1,H) bf16  -> hid (E,T,D) bf16
// 128x128 tile, BK=64, 4 waves (2x2), 4x4 16x16x32 frags/wave.
// grid: (N1/128=45, T/128=16, E=8), block 256.
// ---------------------------------------------------------------------------
__global__ __launch_bounds__(256) void gemm1_act(
    const u16* __restrict__ x, const u16* __restrict__ w1t,
    const float* __restrict__ b1, const float* __restrict__ rw,
    u16* __restrict__ hid)
{
    __shared__ __align__(16) u16 As[128 * 64];
    __shared__ __align__(16) u16 Bs[128 * 64];
    const int tid  = threadIdx.x;
    const int lane = tid & 63;
    const int wid  = tid >> 6;
    const int wr = wid >> 1, wc = wid & 1;
    const int e  = blockIdx.z;
    const int m0 = blockIdx.y * 128;
    const int n0 = blockIdx.x * 128;

    const u16* Ag = x   + (size_t)m0 * HDIM;
    const u16* Bg = w1t + (size_t)e * N1 * HDIM + (size_t)n0 * HDIM;

    f32x4 acc[4][4] = {};
    const int r_ = tid >> 3;    // staging row within 32-row group
    const int c_ = tid & 7;     // staging 16B-chunk slot

    for (int k0 = 0; k0 < HDIM; k0 += 64) {
#pragma unroll
        for (int i = 0; i < 4; ++i) {           // A tile: 128 rows
            int r  = i * 32 + r_;
            int cs = c_ ^ (r & 7);              // xor-swizzled chunk
            GLD16(Ag + (size_t)r * HDIM + k0 + (cs << 3), &As[(i * 256 + tid) << 3]);
        }
#pragma unroll
        for (int i = 0; i < 4; ++i) {           // B tile: 128 rows
            int r  = i * 32 + r_;
            int cs = c_ ^ (r & 7);
            GLD16(Bg + (size_t)r * HDIM + k0 + (cs << 3), &Bs[(i * 256 + tid) << 3]);
        }
        __syncthreads();
#pragma unroll
        for (int kk = 0; kk < 64; kk += 32) {
            const int kq = kk + ((lane >> 4) << 3);
            bf16x8 av[4], bv[4];
#pragma unroll
            for (int f = 0; f < 4; ++f) {
                int ra = wr * 64 + f * 16 + (lane & 15);
                av[f] = *(const bf16x8*)&As[ra * 64 + (((kq >> 3) ^ (ra & 7)) << 3)];
                int rb = wc * 64 + f * 16 + (lane & 15);
                bv[f] = *(const bf16x8*)&Bs[rb * 64 + (((kq >> 3) ^ (rb & 7)) << 3)];
            }
#pragma unroll
            for (int fm = 0; fm < 4; ++fm)
#pragma unroll
                for (int fn = 0; fn < 4; ++fn)
                    acc[fm][fn] = __builtin_amdgcn_mfma_f32_16x16x32_bf16(
                        av[fm], bv[fn], acc[fm][fn], 0, 0, 0);
        }
        __syncthreads();
    }

    // Epilogue: +bias, gate/up pairing via shfl_xor(1), act, *rw, store bf16.
    const int col_l = lane & 15;
    const int row_l = (lane >> 4) << 2;
    float biasv[4]; int ncol[4];
#pragma unroll
    for (int fn = 0; fn < 4; ++fn) {
        ncol[fn]  = n0 + wc * 64 + fn * 16 + col_l;
        biasv[fn] = b1[e * N1 + ncol[fn]];
    }
#pragma unroll
    for (int fm = 0; fm < 4; ++fm) {
#pragma unroll
        for (int reg = 0; reg < 4; ++reg) {
            int t = m0 + wr * 64 + fm * 16 + row_l + reg;
            float rwt = rw[t * NEXP + e];
#pragma unroll
            for (int fn = 0; fn < 4; ++fn) {
                float v = acc[fm][fn][reg] + biasv[fn];
                float o = __shfl_xor(v, 1, 64);     // partner column (gate<->up)
                if ((lane & 1) == 0) {              // even lane = gate column
                    float g = fminf(v, 7.f);
                    float u = fminf(fmaxf(o, -7.f), 7.f);
                    float glu = g / (1.f + __expf(-1.702f * g));
                    float h = (u + 1.f) * glu * rwt;
                    hid[(size_t)e * T_TOK * DDIM + (size_t)t * DDIM + (ncol[fn] >> 1)] = f2bf(h);
                }
            }
        }
    }
}

// ---------------------------------------------------------------------------
// GEMM2 + expert sum + routed down-bias.
//   A = hid (E,T,D)  B = w2t (E,H,D)  -> out (T,H) fp32-or-bf16
// 128x64 tile, BK=64, K-loop over (e, k). 4x2 frags/wave.
// grid: (H/64=45, T/128=16), block 256.
// ---------------------------------------------------------------------------
__global__ __launch_bounds__(256) void gemm2_k(
    const u16* __restrict__ hid, const u16* __restrict__ w2t,
    const float* __restrict__ db, const float* __restrict__ rw,
    void* __restrict__ out, const int* __restrict__ flag)
{
    __shared__ __align__(16) u16 As[128 * 64];
    __shared__ __align__(16) u16 Bs[64 * 64];
    const int tid  = threadIdx.x;
    const int lane = tid & 63;
    const int wid  = tid >> 6;
    const int wr = wid >> 1, wc = wid & 1;
    const int m0 = blockIdx.y * 128;
    const int n0 = blockIdx.x * 64;

    f32x4 acc[4][2] = {};
    const int r_ = tid >> 3;
    const int c_ = tid & 7;

    for (int e = 0; e < NEXP; ++e) {
        const u16* Ag = hid + ((size_t)e * T_TOK + m0) * DDIM;
        const u16* Bg = w2t + ((size_t)e * HDIM + n0) * DDIM;
        for (int k0 = 0; k0 < DDIM; k0 += 64) {
#pragma unroll
            for (int i = 0; i < 4; ++i) {
                int r  = i * 32 + r_;
                int cs = c_ ^ (r & 7);
                GLD16(Ag + (size_t)r * DDIM + k0 + (cs << 3), &As[(i * 256 + tid) << 3]);
            }
#pragma unroll
            for (int i = 0; i < 2; ++i) {
                int r  = i * 32 + r_;
                int cs = c_ ^ (r & 7);
                GLD16(Bg + (size_t)r * DDIM + k0 + (cs << 3), &Bs[(i * 256 + tid) << 3]);
            }
            __syncthreads();
#pragma unroll
            for (int kk = 0; kk < 64; kk += 32) {
                const int kq = kk + ((lane >> 4) << 3);
                bf16x8 av[4], bv[2];
#pragma unroll
                for (int f = 0; f < 4; ++f) {
                    int ra = wr * 64 + f * 16 + (lane & 15);
                    av[f] = *(const bf16x8*)&As[ra * 64 + (((kq >> 3) ^ (ra & 7)) << 3)];
                }
#pragma unroll
                for (int f = 0; f < 2; ++f) {
                    int rb = wc * 32 + f * 16 + (lane & 15);
                    bv[f] = *(const bf16x8*)&Bs[rb * 64 + (((kq >> 3) ^ (rb & 7)) << 3)];
                }
#pragma unroll
                for (int fm = 0; fm < 4; ++fm)
#pragma unroll
                    for (int fn = 0; fn < 2; ++fn)
                        acc[fm][fn] = __builtin_amdgcn_mfma_f32_16x16x32_bf16(
                            av[fm], bv[fn], acc[fm][fn], 0, 0, 0);
            }
            __syncthreads();
        }
    }

    // Epilogue: + sum_e rw(t,e)*db(e,h), store (dtype per flag).
    const int isf32 = *flag;
    const int col_l = lane & 15;
    const int row_l = (lane >> 4) << 2;
    float dbv[2][8]; int hcol[2];
#pragma unroll
    for (int fn = 0; fn < 2; ++fn) {
        hcol[fn] = n0 + wc * 32 + fn * 16 + col_l;
#pragma unroll
        for (int e = 0; e < NEXP; ++e) dbv[fn][e] = db[e * HDIM + hcol[fn]];
    }
#pragma unroll
    for (int fm = 0; fm < 4; ++fm) {
#pragma unroll
        for (int reg = 0; reg < 4; ++reg) {
            int t = m0 + wr * 64 + fm * 16 + row_l + reg;
            float rwf[8];
#pragma unroll
            for (int e = 0; e < NEXP; ++e) rwf[e] = rw[t * NEXP + e];
#pragma unroll
            for (int fn = 0; fn < 2; ++fn) {
                float bias = 0.f;
#pragma unroll
                for (int e = 0; e < NEXP; ++e) bias += rwf[e] * dbv[fn][e];
                float val = acc[fm][fn][reg] + bias;
                size_t off = (size_t)t * HDIM + hcol[fn];
                if (isf32) ((float*)out)[off] = val;
                else       ((u16*)out)[off]  = f2bf(val);
            }
        }
    }
}

// ---------------------------------------------------------------------------
extern "C" void kernel_launch(void* const* d_in, const int* in_sizes, int n_in,
                              void* d_out, int out_size, void* d_ws, size_t ws_size,
                              hipStream_t stream)
{
    const void* x  = d_in[0];   // (T,H)
    const void* rw = d_in[1];   // (T,E)
    const void* w1 = d_in[2];   // (E,H,2D)
    const void* b1 = d_in[3];   // (E,2D)
    const void* w2 = d_in[4];   // (E,D,H)
    const void* db = d_in[5];   // (E,H)

    char* ws = (char*)d_ws;
    size_t off = 0;
    int*   flag = (int*)(ws + off);   off += 256;
    float* rw_f = (float*)(ws + off); off += (size_t)NRW * 4;
    float* b1_f = (float*)(ws + off); off += (size_t)NB1 * 4;
    float* db_f = (float*)(ws + off); off += (size_t)NDB * 4;
    u16*   xc   = (u16*)(ws + off);   off += (size_t)T_TOK * HDIM * 2;
    u16*   hid  = (u16*)(ws + off);   off += (size_t)NEXP * T_TOK * DDIM * 2;
    u16*   wbig = (u16*)(ws + off);   // max(E*N1*H, E*H*D) bf16 = 265.4 MB

    dim3 blk(256);
    detect_k<<<1, blk, 0, stream>>>((const u16*)x, flag);
    cast_small_k<<<(NRW + NB1 + NDB) / 256, blk, 0, stream>>>(
        rw, b1, db, rw_f, b1_f, db_f, flag);
    cast_x_k<<<(T_TOK * HDIM / 4) / 256, blk, 0, stream>>>(x, xc, flag);
    // w1 (E,H,2D) -> wbig = w1t (E,2D,H)
    transpose_cast_k<<<dim3(N1 / 64, HDIM / 64, NEXP), blk, 0, stream>>>(
        w1, wbig, HDIM, N1, flag);
    gemm1_act<<<dim3(N1 / 128, T_TOK / 128, NEXP), blk, 0, stream>>>(
        xc, wbig, b1_f, rw_f, hid);
    // w2 (E,D,H) -> wbig = w2t (E,H,D)   (w1t no longer needed)
    transpose_cast_k<<<dim3(HDIM / 64, DDIM / 64, NEXP), blk, 0, stream>>>(
        w2, wbig, DDIM, HDIM, flag);
    gemm2_k<<<dim3(HDIM / 64, T_TOK / 128, 1), blk, 0, stream>>>(
        hid, wbig, db_f, rw_f, d_out, flag);
}